// Round 12
// baseline (118.779 us; speedup 1.0000x reference)
//
#include <hip/hip_runtime.h>
#include <math.h>

#define BB 32
#define LL 200
#define HH 64
#define HSS 32
#define HB 64
#define TRI (LL*(LL+1)/2)          // 20100 triangle rows per hb
#define ROWS 1280                  // triangle rows per mlp block (20 passes)
#define NEGV (-4294967295.0f)

typedef __bf16 bf16x8 __attribute__((ext_vector_type(8)));
typedef float f32x4 __attribute__((ext_vector_type(4)));

// ---------------------------------------------------------------------------
// Kernel A: QKV projections into split-head layout  Qs/Ks/Vs [HB][L][HS].
// 256 threads / 4 rows per block. First 16 blocks also convert Wt -> bf16.
// ---------------------------------------------------------------------------
__global__ __launch_bounds__(256) void proj_kernel(
    const float* __restrict__ q_in, const float* __restrict__ k_in,
    const float* __restrict__ v_in,
    const float* __restrict__ Wq, const float* __restrict__ bq,
    const float* __restrict__ Wk, const float* __restrict__ bk,
    const float* __restrict__ Wv, const float* __restrict__ bv,
    const float* __restrict__ Wt, unsigned short* __restrict__ WtT,
    float* __restrict__ Qs, float* __restrict__ Ks, float* __restrict__ Vs)
{
    const int tid = threadIdx.x;
    const int row = blockIdx.x*4 + (tid >> 6);   // b*L + l
    const int b = row / LL, l = row % LL;
    const int j = tid & 63;                      // output channel 0..63
    const int g = tid >> 6;                      // row group 0..3

    // fused prep: WtT[n*64+k] = bf16(Wt[k*64+n])
    if (blockIdx.x < 16) {
        const int t = blockIdx.x*256 + tid;      // t = n*64 + k
        const int n = t >> 6, k = t & 63;
        const __bf16 h = (__bf16)Wt[k*HH + n];
        WtT[t] = __builtin_bit_cast(unsigned short, h);
    }

    __shared__ float s[4][3][HH];
    s[g][0][j] = q_in[row*HH + j];
    s[g][1][j] = k_in[row*HH + j];
    s[g][2][j] = v_in[row*HH + j];
    __syncthreads();

    const float* W[3]    = {Wq, Wk, Wv};
    const float* bias[3] = {bq, bk, bv};
    float*       dst[3]  = {Qs, Ks, Vs};

    const int hb  = (j >> 5)*BB + b;                 // head*B + b
    const int idx = (hb*LL + l)*HSS + (j & 31);

    #pragma unroll
    for (int m = 0; m < 3; ++m) {
        float acc = bias[m][j];
        #pragma unroll
        for (int i = 0; i < HH; ++i)
            acc = fmaf(s[g][m][i], W[m][i*HH + j], acc);
        dst[m][idx] = acc;
    }
}

// ---------------------------------------------------------------------------
// Kernel M: dense triangle MLP. Each block = 1280 consecutive rows of one
// hb's lower triangle {(q,k): k<=q}; grid 16 x 64 = 1024 blocks = exactly
// 4 resident blocks/CU on 256 CUs -> ONE occupancy generation.
// Rows resolved to (q,k) once into an LDS base table, then 20 uniform
// passes: pair-packed staging (32B global reads, ds_write_b128) -> bf16
// swizzled LDS -> MFMA -> channel-reduce -> scatter p.
// 2-deep register pipeline, lgkm-only barriers.
// ---------------------------------------------------------------------------
__global__ __launch_bounds__(256) void mlp_kernel(
    const float* __restrict__ T,                 // [HB, L, L, H] fp32
    const unsigned short* __restrict__ WtT,      // bf16 [n][k]
    const float* __restrict__ bt, const float* __restrict__ Wp,
    float* __restrict__ Plog)                    // [HB*L*L], hb*40000+q*200+k
{
    const int hb   = blockIdx.y;
    const int r0   = blockIdx.x * ROWS;
    const int tid  = threadIdx.x;
    const int wave = tid >> 6;
    const int lane = tid & 63;
    const int bl   = lane & 15;                  // B-col / C-channel low bits
    const int bg   = lane >> 4;                  // k-group / C-row group

    __shared__ __align__(16) unsigned short sA[2][64*HH];  // 2 x 8 KB
    __shared__ int sBase[ROWS];                  // float4 index of row in T

    // ---- resolve triangle row -> (q,k) -> T row base (once) ----
    #pragma unroll
    for (int j = 0; j < ROWS/256; ++j) {
        const int rr = j*256 + tid;
        int r = r0 + rr;
        if (r >= TRI) r = TRI - 1;                 // clamp (store guarded)
        const float s = sqrtf((float)(8*r + 1));
        int qq = (int)((s - 1.0f) * 0.5f);
        while ((qq + 1)*(qq + 2)/2 <= r) ++qq;     // integer fixup
        while (qq*(qq + 1)/2 > r) --qq;
        const int kk = r - qq*(qq + 1)/2;
        sBase[rr] = ((hb*LL + qq)*LL + kk) << 4;   // float4 units
    }
    __syncthreads();

    const float4* T4 = reinterpret_cast<const float4*>(T);

    // pair mapping: 512 pairs/pass; thread handles pairs tid and 256+tid.
    // pair p: row = p>>3 (0..63), cp = p&7 -> float4 slots cp*2, cp*2+1
    // (32B contiguous per thread; 16B-aligned chunk survives the XOR swizzle
    //  since the mask (row&7)<<4 only touches bits >= 4)
#define LOADCHUNK(CUR, c)                                                      \
    {                                                                          \
        _Pragma("unroll")                                                      \
        for (int j = 0; j < 2; ++j) {                                          \
            const int p = j*256 + tid;                                         \
            const int base = sBase[(c)*64 + (p >> 3)] + (p & 7)*2;             \
            CUR[2*j]   = T4[base];                                             \
            CUR[2*j+1] = T4[base + 1];                                         \
        }                                                                      \
    }

    // ---- issue pass 0 AND pass 1 loads first (2-deep pipeline) ----
    float4 va[4], vb[4];
    LOADCHUNK(va, 0)
    LOADCHUNK(vb, 1)

    // ---- B fragments (Wt), bt/Wp per-lane channel coefs (L2-hot) ----
    bf16x8 bfrag[4][2];
    float  btv[4], wpv[4];
    #pragma unroll
    for (int n = 0; n < 4; ++n) {
        #pragma unroll
        for (int k = 0; k < 2; ++k) {
            const uint4 raw = *reinterpret_cast<const uint4*>(
                WtT + ((n*16 + bl)*HH + k*32 + bg*8));
            bfrag[n][k] = __builtin_bit_cast(bf16x8, raw);
        }
        btv[n] = bt[n*16 + bl];
        wpv[n] = Wp[n*16 + bl];
    }

#define PACK_ISSUE_COMPUTE(c, CUR, DO_ISSUE, NC)                               \
    {                                                                          \
        /* pack pass c (waits vmcnt on CUR) into LDS buffer c&1 */             \
        _Pragma("unroll")                                                      \
        for (int j = 0; j < 2; ++j) {                                          \
            const int p = j*256 + tid;                                         \
            const int row = p >> 3, cp = p & 7;                                \
            union { __bf16 h[8]; uint4 u4; } pk;                               \
            pk.h[0] = (__bf16)CUR[2*j].x;   pk.h[1] = (__bf16)CUR[2*j].y;      \
            pk.h[2] = (__bf16)CUR[2*j].z;   pk.h[3] = (__bf16)CUR[2*j].w;      \
            pk.h[4] = (__bf16)CUR[2*j+1].x; pk.h[5] = (__bf16)CUR[2*j+1].y;    \
            pk.h[6] = (__bf16)CUR[2*j+1].z; pk.h[7] = (__bf16)CUR[2*j+1].w;    \
            const int byteoff = row*128 + ((cp*16) ^ ((row & 7) << 4));        \
            *reinterpret_cast<uint4*>(                                         \
                reinterpret_cast<char*>(sA[(c) & 1]) + byteoff) = pk.u4;       \
        }                                                                      \
        if (DO_ISSUE) LOADCHUNK(CUR, NC)   /* WAR: reissue after pack */       \
        /* lgkm-only barrier: ds ops drained, global loads stay in flight */   \
        asm volatile("s_waitcnt lgkmcnt(0)" ::: "memory");                     \
        __builtin_amdgcn_s_barrier();                                          \
                                                                               \
        const int arow = wave*16 + bl;                                         \
        bf16x8 afrag[2];                                                       \
        _Pragma("unroll")                                                      \
        for (int k = 0; k < 2; ++k) {                                          \
            const int abyte = arow*128 + ((k*64 + bg*16) ^ ((arow & 7) << 4)); \
            const uint4 raw = *reinterpret_cast<const uint4*>(                 \
                reinterpret_cast<const char*>(sA[(c) & 1]) + abyte);           \
            afrag[k] = __builtin_bit_cast(bf16x8, raw);                        \
        }                                                                      \
        f32x4 acc[4];                                                          \
        _Pragma("unroll")                                                      \
        for (int n = 0; n < 4; ++n) {                                          \
            acc[n] = (f32x4){0.f, 0.f, 0.f, 0.f};                              \
            acc[n] = __builtin_amdgcn_mfma_f32_16x16x32_bf16(                  \
                         afrag[0], bfrag[n][0], acc[n], 0, 0, 0);              \
            acc[n] = __builtin_amdgcn_mfma_f32_16x16x32_bf16(                  \
                         afrag[1], bfrag[n][1], acc[n], 0, 0, 0);              \
        }                                                                      \
        float p[4] = {0.f, 0.f, 0.f, 0.f};                                     \
        _Pragma("unroll")                                                      \
        for (int n = 0; n < 4; ++n) {                                          \
            _Pragma("unroll")                                                  \
            for (int r = 0; r < 4; ++r)                                        \
                p[r] = fmaf(fmaxf(acc[n][r] + btv[n], 0.f), wpv[n], p[r]);     \
        }                                                                      \
        _Pragma("unroll")                                                      \
        for (int m = 1; m < 16; m <<= 1) {                                     \
            _Pragma("unroll")                                                  \
            for (int r = 0; r < 4; ++r) p[r] += __shfl_xor(p[r], m, 64);       \
        }                                                                      \
        if (bl == 0) {                                                         \
            _Pragma("unroll")                                                  \
            for (int r = 0; r < 4; ++r) {                                      \
                const int lr = (c)*64 + wave*16 + bg*4 + r;                    \
                if (r0 + lr < TRI)                                             \
                    Plog[sBase[lr] >> 4] = p[r];   /* = hb*40000+q*200+k */    \
            }                                                                  \
        }                                                                      \
    }

    PACK_ISSUE_COMPUTE( 0, va, 1,  2)
    PACK_ISSUE_COMPUTE( 1, vb, 1,  3)
    PACK_ISSUE_COMPUTE( 2, va, 1,  4)
    PACK_ISSUE_COMPUTE( 3, vb, 1,  5)
    PACK_ISSUE_COMPUTE( 4, va, 1,  6)
    PACK_ISSUE_COMPUTE( 5, vb, 1,  7)
    PACK_ISSUE_COMPUTE( 6, va, 1,  8)
    PACK_ISSUE_COMPUTE( 7, vb, 1,  9)
    PACK_ISSUE_COMPUTE( 8, va, 1, 10)
    PACK_ISSUE_COMPUTE( 9, vb, 1, 11)
    PACK_ISSUE_COMPUTE(10, va, 1, 12)
    PACK_ISSUE_COMPUTE(11, vb, 1, 13)
    PACK_ISSUE_COMPUTE(12, va, 1, 14)
    PACK_ISSUE_COMPUTE(13, vb, 1, 15)
    PACK_ISSUE_COMPUTE(14, va, 1, 16)
    PACK_ISSUE_COMPUTE(15, vb, 1, 17)
    PACK_ISSUE_COMPUTE(16, va, 1, 18)
    PACK_ISSUE_COMPUTE(17, vb, 1, 19)
    PACK_ISSUE_COMPUTE(18, va, 0,  0)
    PACK_ISSUE_COMPUTE(19, vb, 0,  0)
#undef PACK_ISSUE_COMPUTE
#undef LOADCHUNK
}

// ---------------------------------------------------------------------------
// Kernel B: QK^T + combine log(sigmoid(p)) + mask + softmax + PV for TWO
// query rows (q, q+100) per block: one K/V load feeds both rows' math.
// grid (100, 64). Reads p from attn region of d_out, overwrites with attn.
// ---------------------------------------------------------------------------
__global__ __launch_bounds__(256) void attn2_kernel(
    const float* __restrict__ Qs, const float* __restrict__ Ks,
    const float* __restrict__ Vs,
    const int*   __restrict__ time_mask,         // [B, L] int32
    const float* __restrict__ bp,
    float* __restrict__ out, float* __restrict__ attn_out /* = Plog in */)
{
    const int q0   = blockIdx.x;                 // 0..99
    const int q1   = q0 + 100;
    const int hb   = blockIdx.y;
    const int b    = hb & (BB-1);
    const int head = hb >> 5;
    const int tid  = threadIdx.x;
    const int wave = tid >> 6;
    const int lane = tid & 63;

    __shared__ float sQ[2][HSS];
    __shared__ float sLogit[2][LL];
    __shared__ float sRed[2][8];
    __shared__ float sO[2][8][HSS];

    const bool qm0 = (time_mask[b*LL + q0] != 0);
    const bool qm1 = (time_mask[b*LL + q1] != 0);
    const bool live0 = (tid < LL) && !qm0 && (tid <= q0);
    const bool live1 = (tid < LL) && !qm1 && (tid <= q1);

    // hoisted: issue p loads before the barrier (hide under setup)
    float pv0 = 0.0f, pv1 = 0.0f;
    if (live0) pv0 = attn_out[((size_t)hb*LL + q0)*LL + tid];
    if (live1) pv1 = attn_out[((size_t)hb*LL + q1)*LL + tid];

    if (tid < 2*HSS)
        sQ[tid >> 5][tid & 31] =
            Qs[(hb*LL + ((tid < HSS) ? q0 : q1))*HSS + (tid & 31)];
    const float bp0 = bp[0];
    const float scale = 0.17677669529663687f;    // 1/sqrt(32)
    __syncthreads();

    if (tid < LL) {
        float l0 = NEGV, l1 = NEGV;
        if (live0 || live1) {
            const float4* kr = reinterpret_cast<const float4*>(
                Ks + (hb*LL + tid)*HSS);
            float qk0 = 0.0f, qk1 = 0.0f;
            #pragma unroll
            for (int i = 0; i < 8; ++i) {
                const float4 kv = kr[i];      // one K load, two dot products
                qk0 += kv.x*sQ[0][4*i+0] + kv.y*sQ[0][4*i+1]
                     + kv.z*sQ[0][4*i+2] + kv.w*sQ[0][4*i+3];
                qk1 += kv.x*sQ[1][4*i+0] + kv.y*sQ[1][4*i+1]
                     + kv.z*sQ[1][4*i+2] + kv.w*sQ[1][4*i+3];
            }
            if (live0) {
                const float x = pv0 + bp0;
                l0 = (qk0 - logf(1.0f + expf(-x))) * scale;
            }
            if (live1) {
                const float x = pv1 + bp0;
                l1 = (qk1 - logf(1.0f + expf(-x))) * scale;
            }
        }
        sLogit[0][tid] = l0;
        sLogit[1][tid] = l1;
    }
    __syncthreads();

    // ---- softmax over 200 logits, both rows (all-NEG -> uniform 1/200) ----
    const float v0 = (tid < LL) ? sLogit[0][tid] : -INFINITY;
    const float v1 = (tid < LL) ? sLogit[1][tid] : -INFINITY;
    float m0 = v0, m1 = v1;
    #pragma unroll
    for (int s = 1; s < 64; s <<= 1) {
        m0 = fmaxf(m0, __shfl_xor(m0, s, 64));
        m1 = fmaxf(m1, __shfl_xor(m1, s, 64));
    }
    if (lane == 0) { sRed[0][wave] = m0; sRed[1][wave] = m1; }
    __syncthreads();
    const float rmax0 = fmaxf(fmaxf(sRed[0][0], sRed[0][1]),
                              fmaxf(sRed[0][2], sRed[0][3]));
    const float rmax1 = fmaxf(fmaxf(sRed[1][0], sRed[1][1]),
                              fmaxf(sRed[1][2], sRed[1][3]));

    const float e0 = (tid < LL) ? expf(v0 - rmax0) : 0.0f;
    const float e1 = (tid < LL) ? expf(v1 - rmax1) : 0.0f;
    float s0 = e0, s1 = e1;
    #pragma unroll
    for (int s = 1; s < 64; s <<= 1) {
        s0 += __shfl_xor(s0, s, 64);
        s1 += __shfl_xor(s1, s, 64);
    }
    if (lane == 0) { sRed[0][4 + wave] = s0; sRed[1][4 + wave] = s1; }
    __syncthreads();
    const float rsum0 = sRed[0][4] + sRed[0][5] + sRed[0][6] + sRed[0][7];
    const float rsum1 = sRed[1][4] + sRed[1][5] + sRed[1][6] + sRed[1][7];
    const float a0 = e0 * (1.0f / rsum0);
    const float a1 = e1 * (1.0f / rsum1);

    if (tid < LL) {
        sLogit[0][tid] = a0;
        sLogit[1][tid] = a1;
        attn_out[((size_t)hb*LL + q0)*LL + tid] = a0;
        attn_out[((size_t)hb*LL + q1)*LL + tid] = a1;
    }
    __syncthreads();

    // ---- out[d] = sum_k a[k] * V[hb][k][d], both rows share the V load ----
    {
        const int d = tid & 31;
        const int g = tid >> 5;            // 0..7, 25 keys each
        float acc0 = 0.0f, acc1 = 0.0f;
        for (int k = g*25; k < g*25 + 25; ++k) {
            const float vv = Vs[(hb*LL + k)*HSS + d];
            acc0 = fmaf(sLogit[0][k], vv, acc0);
            acc1 = fmaf(sLogit[1][k], vv, acc1);
        }
        sO[0][g][d] = acc0;
        sO[1][g][d] = acc1;
        __syncthreads();
        if (tid < 2*HSS) {
            const int which = tid >> 5, d2 = tid & 31;
            float o = 0.0f;
            #pragma unroll
            for (int g2 = 0; g2 < 8; ++g2) o += sO[which][g2][d2];
            out[((size_t)b*LL + (which ? q1 : q0))*HH + head*HSS + d2] = o;
        }
    }
}

// ---------------------------------------------------------------------------
extern "C" void kernel_launch(void* const* d_in, const int* in_sizes, int n_in,
                              void* d_out, int out_size, void* d_ws, size_t ws_size,
                              hipStream_t stream) {
    const float* queries = (const float*)d_in[0];
    const float* keys    = (const float*)d_in[1];
    const float* values  = (const float*)d_in[2];
    const float* T       = (const float*)d_in[3];
    const int*   tmask   = (const int*)d_in[4];
    // d_in[5] = attn_mask (causal triu, computed on the fly -> unused)
    const float* Wq = (const float*)d_in[6];
    const float* bq = (const float*)d_in[7];
    const float* Wk = (const float*)d_in[8];
    const float* bk = (const float*)d_in[9];
    const float* Wv = (const float*)d_in[10];
    const float* bv = (const float*)d_in[11];
    const float* Wt = (const float*)d_in[12];
    const float* bt = (const float*)d_in[13];
    const float* Wp = (const float*)d_in[14];
    const float* bp = (const float*)d_in[15];

    float* Qs = (float*)d_ws;
    float* Ks = Qs + HB*LL*HSS;
    float* Vs = Ks + HB*LL*HSS;
    unsigned short* WtT = (unsigned short*)(Vs + HB*LL*HSS);

    float* out      = (float*)d_out;
    float* attn_out = out + BB*LL*HH;            // doubles as Plog scratch

    proj_kernel<<<BB*LL/4, 256, 0, stream>>>(queries, keys, values,
                                             Wq, bq, Wk, bk, Wv, bv,
                                             Wt, WtT, Qs, Ks, Vs);

    dim3 mgrid((TRI + ROWS - 1) / ROWS, HB);     // 16 x 64 = 1024 blocks
    mlp_kernel<<<mgrid, 256, 0, stream>>>(T, WtT, bt, Wp, attn_out);

    dim3 agrid(LL/2, HB);                        // 100 x 64, 2 q per block
    attn2_kernel<<<agrid, 256, 0, stream>>>(Qs, Ks, Vs, tmask, bp,
                                            out, attn_out);
}

// Round 13
// 113.216 us; speedup vs baseline: 1.0491x; 1.0491x over previous
//
#include <hip/hip_runtime.h>
#include <math.h>

#define BB 32
#define LL 200
#define HH 64
#define HSS 32
#define HB 64
#define TRI (LL*(LL+1)/2)          // 20100 triangle rows per hb
#define ROWS 640                   // triangle rows per mlp block (10 passes)
#define NEGV (-4294967295.0f)

typedef __bf16 bf16x8 __attribute__((ext_vector_type(8)));
typedef float f32x4 __attribute__((ext_vector_type(4)));

// ---------------------------------------------------------------------------
// Kernel A: QKV projections into split-head layout  Qs/Ks/Vs [HB][L][HS].
// First 64 blocks additionally convert Wt -> WtT bf16 (fused prep).
// ---------------------------------------------------------------------------
__global__ __launch_bounds__(64) void proj_kernel(
    const float* __restrict__ q_in, const float* __restrict__ k_in,
    const float* __restrict__ v_in,
    const float* __restrict__ Wq, const float* __restrict__ bq,
    const float* __restrict__ Wk, const float* __restrict__ bk,
    const float* __restrict__ Wv, const float* __restrict__ bv,
    const float* __restrict__ Wt, unsigned short* __restrict__ WtT,
    float* __restrict__ Qs, float* __restrict__ Ks, float* __restrict__ Vs)
{
    const int row = blockIdx.x;            // b*L + l
    const int b = row / LL, l = row % LL;
    const int j = threadIdx.x;             // output channel 0..63

    // fused prep: WtT[n*64+k] = bf16(Wt[k*64+n])
    if (blockIdx.x < 64) {
        const int t = blockIdx.x*64 + j;   // t = n*64 + k
        const int n = t >> 6, k = t & 63;
        const __bf16 h = (__bf16)Wt[k*HH + n];
        WtT[t] = __builtin_bit_cast(unsigned short, h);
    }

    __shared__ float s[3][HH];
    s[0][j] = q_in[row*HH + j];
    s[1][j] = k_in[row*HH + j];
    s[2][j] = v_in[row*HH + j];
    __syncthreads();

    const float* W[3]    = {Wq, Wk, Wv};
    const float* bias[3] = {bq, bk, bv};
    float*       dst[3]  = {Qs, Ks, Vs};

    const int hb  = (j >> 5)*BB + b;                 // head*B + b
    const int idx = (hb*LL + l)*HSS + (j & 31);

    #pragma unroll
    for (int m = 0; m < 3; ++m) {
        float acc = bias[m][j];
        #pragma unroll
        for (int i = 0; i < HH; ++i)
            acc = fmaf(s[m][i], W[m][i*HH + j], acc);
        dst[m][idx] = acc;
    }
}

// ---------------------------------------------------------------------------
// Kernel M: dense triangle MLP. Each block = 640 consecutive rows of one
// hb's lower triangle {(q,k): k<=q}; grid 32 x 64 = 2048 blocks (exactly
// 8 per CU, 2 clean occupancy generations at 4 resident blocks/CU).
// Rows resolved to (q,k) once into an LDS base table, then 10 uniform
// passes of coalesced staging -> bf16 swizzled LDS -> MFMA -> reduce ->
// scatter p. 2-deep register pipeline, lgkm-only barriers.
// ---------------------------------------------------------------------------
__global__ __launch_bounds__(256) void mlp_kernel(
    const float* __restrict__ T,                 // [HB, L, L, H] fp32
    const unsigned short* __restrict__ WtT,      // bf16 [n][k]
    const float* __restrict__ bt, const float* __restrict__ Wp,
    float* __restrict__ Plog)                    // [HB*L*L], hb*40000+q*200+k
{
    const int hb   = blockIdx.y;
    const int r0   = blockIdx.x * ROWS;
    const int tid  = threadIdx.x;
    const int wave = tid >> 6;
    const int lane = tid & 63;
    const int bl   = lane & 15;                  // B-col / C-channel low bits
    const int bg   = lane >> 4;                  // k-group / C-row group

    __shared__ __align__(16) unsigned short sA[2][64*HH];  // 2 x 8 KB
    __shared__ int sBase[ROWS];                  // float4 index of row in T

    // ---- resolve triangle row -> (q,k) -> T row base (once) ----
    #pragma unroll
    for (int j = 0; j < 3; ++j) {
        const int rr = j*256 + tid;
        if (rr < ROWS) {
            int r = r0 + rr;
            if (r >= TRI) r = TRI - 1;                 // clamp (store guarded)
            const float s = sqrtf((float)(8*r + 1));
            int qq = (int)((s - 1.0f) * 0.5f);
            while ((qq + 1)*(qq + 2)/2 <= r) ++qq;     // integer fixup
            while (qq*(qq + 1)/2 > r) --qq;
            const int kk = r - qq*(qq + 1)/2;
            sBase[rr] = ((hb*LL + qq)*LL + kk) << 4;   // float4 units
        }
    }
    __syncthreads();

    const float4* T4 = reinterpret_cast<const float4*>(T);

#define LOADCHUNK(CUR, c)                                                      \
    {                                                                          \
        _Pragma("unroll")                                                      \
        for (int i = 0; i < 4; ++i) {                                          \
            const int g = i*256 + tid;                                         \
            CUR[i] = T4[sBase[(c)*64 + (g >> 4)] + (g & 15)];                  \
        }                                                                      \
    }

    // ---- issue pass 0 AND pass 1 loads first (2-deep pipeline) ----
    float4 va[4], vb[4];
    LOADCHUNK(va, 0)
    LOADCHUNK(vb, 1)

    // ---- B fragments (Wt), bt/Wp per-lane channel coefs (L2-hot) ----
    bf16x8 bfrag[4][2];
    float  btv[4], wpv[4];
    #pragma unroll
    for (int n = 0; n < 4; ++n) {
        #pragma unroll
        for (int k = 0; k < 2; ++k) {
            const uint4 raw = *reinterpret_cast<const uint4*>(
                WtT + ((n*16 + bl)*HH + k*32 + bg*8));
            bfrag[n][k] = __builtin_bit_cast(bf16x8, raw);
        }
        btv[n] = bt[n*16 + bl];
        wpv[n] = Wp[n*16 + bl];
    }

#define PACK_ISSUE_COMPUTE(c, CUR, DO_ISSUE, NC)                               \
    {                                                                          \
        /* pack pass c (waits vmcnt on CUR) into LDS buffer c&1 */             \
        _Pragma("unroll")                                                      \
        for (int i = 0; i < 4; ++i) {                                          \
            const int g = i*256 + tid;                                         \
            const int row = g >> 4, cf4 = g & 15;                              \
            union { __bf16 h[4]; uint2 u2; } pk;                               \
            pk.h[0] = (__bf16)CUR[i].x; pk.h[1] = (__bf16)CUR[i].y;            \
            pk.h[2] = (__bf16)CUR[i].z; pk.h[3] = (__bf16)CUR[i].w;            \
            const int byteoff = row*128 + ((cf4*8) ^ ((row & 7) << 4));        \
            *reinterpret_cast<uint2*>(                                         \
                reinterpret_cast<char*>(sA[(c) & 1]) + byteoff) = pk.u2;       \
        }                                                                      \
        if (DO_ISSUE) LOADCHUNK(CUR, NC)   /* WAR: reissue after pack */       \
        /* lgkm-only barrier: ds ops drained, global loads stay in flight */   \
        asm volatile("s_waitcnt lgkmcnt(0)" ::: "memory");                     \
        __builtin_amdgcn_s_barrier();                                          \
                                                                               \
        const int arow = wave*16 + bl;                                         \
        bf16x8 afrag[2];                                                       \
        _Pragma("unroll")                                                      \
        for (int k = 0; k < 2; ++k) {                                          \
            const int abyte = arow*128 + ((k*64 + bg*16) ^ ((arow & 7) << 4)); \
            const uint4 raw = *reinterpret_cast<const uint4*>(                 \
                reinterpret_cast<const char*>(sA[(c) & 1]) + abyte);           \
            afrag[k] = __builtin_bit_cast(bf16x8, raw);                        \
        }                                                                      \
        f32x4 acc[4];                                                          \
        _Pragma("unroll")                                                      \
        for (int n = 0; n < 4; ++n) {                                          \
            acc[n] = (f32x4){0.f, 0.f, 0.f, 0.f};                              \
            acc[n] = __builtin_amdgcn_mfma_f32_16x16x32_bf16(                  \
                         afrag[0], bfrag[n][0], acc[n], 0, 0, 0);              \
            acc[n] = __builtin_amdgcn_mfma_f32_16x16x32_bf16(                  \
                         afrag[1], bfrag[n][1], acc[n], 0, 0, 0);              \
        }                                                                      \
        float p[4] = {0.f, 0.f, 0.f, 0.f};                                     \
        _Pragma("unroll")                                                      \
        for (int n = 0; n < 4; ++n) {                                          \
            _Pragma("unroll")                                                  \
            for (int r = 0; r < 4; ++r)                                        \
                p[r] = fmaf(fmaxf(acc[n][r] + btv[n], 0.f), wpv[n], p[r]);     \
        }                                                                      \
        _Pragma("unroll")                                                      \
        for (int m = 1; m < 16; m <<= 1) {                                     \
            _Pragma("unroll")                                                  \
            for (int r = 0; r < 4; ++r) p[r] += __shfl_xor(p[r], m, 64);       \
        }                                                                      \
        if (bl == 0) {                                                         \
            _Pragma("unroll")                                                  \
            for (int r = 0; r < 4; ++r) {                                      \
                const int lr = (c)*64 + wave*16 + bg*4 + r;                    \
                if (r0 + lr < TRI)                                             \
                    Plog[sBase[lr] >> 4] = p[r];   /* = hb*40000+q*200+k */    \
            }                                                                  \
        }                                                                      \
    }

    PACK_ISSUE_COMPUTE(0, va, 1, 2)
    PACK_ISSUE_COMPUTE(1, vb, 1, 3)
    PACK_ISSUE_COMPUTE(2, va, 1, 4)
    PACK_ISSUE_COMPUTE(3, vb, 1, 5)
    PACK_ISSUE_COMPUTE(4, va, 1, 6)
    PACK_ISSUE_COMPUTE(5, vb, 1, 7)
    PACK_ISSUE_COMPUTE(6, va, 1, 8)
    PACK_ISSUE_COMPUTE(7, vb, 1, 9)
    PACK_ISSUE_COMPUTE(8, va, 0, 0)
    PACK_ISSUE_COMPUTE(9, vb, 0, 0)
#undef PACK_ISSUE_COMPUTE
#undef LOADCHUNK
}

// ---------------------------------------------------------------------------
// Kernel B: QK^T + combine log(sigmoid(p)) + mask + softmax + PV for TWO
// query rows (q, q+100) per block: one K/V load feeds both rows' math.
// grid (100, 64). Reads p from attn region of d_out, overwrites with attn.
// ---------------------------------------------------------------------------
__global__ __launch_bounds__(256) void attn2_kernel(
    const float* __restrict__ Qs, const float* __restrict__ Ks,
    const float* __restrict__ Vs,
    const int*   __restrict__ time_mask,         // [B, L] int32
    const float* __restrict__ bp,
    float* __restrict__ out, float* __restrict__ attn_out /* = Plog in */)
{
    const int q0   = blockIdx.x;                 // 0..99
    const int q1   = q0 + 100;
    const int hb   = blockIdx.y;
    const int b    = hb & (BB-1);
    const int head = hb >> 5;
    const int tid  = threadIdx.x;
    const int wave = tid >> 6;
    const int lane = tid & 63;

    __shared__ float sQ[2][HSS];
    __shared__ float sLogit[2][LL];
    __shared__ float sRed[2][8];
    __shared__ float sO[2][8][HSS];

    const bool qm0 = (time_mask[b*LL + q0] != 0);
    const bool qm1 = (time_mask[b*LL + q1] != 0);
    const bool live0 = (tid < LL) && !qm0 && (tid <= q0);
    const bool live1 = (tid < LL) && !qm1 && (tid <= q1);

    // hoisted: issue p loads before the barrier (hide under setup)
    float pv0 = 0.0f, pv1 = 0.0f;
    if (live0) pv0 = attn_out[((size_t)hb*LL + q0)*LL + tid];
    if (live1) pv1 = attn_out[((size_t)hb*LL + q1)*LL + tid];

    if (tid < 2*HSS)
        sQ[tid >> 5][tid & 31] =
            Qs[(hb*LL + ((tid < HSS) ? q0 : q1))*HSS + (tid & 31)];
    const float bp0 = bp[0];
    const float scale = 0.17677669529663687f;    // 1/sqrt(32)
    __syncthreads();

    if (tid < LL) {
        float l0 = NEGV, l1 = NEGV;
        if (live0 || live1) {
            const float4* kr = reinterpret_cast<const float4*>(
                Ks + (hb*LL + tid)*HSS);
            float qk0 = 0.0f, qk1 = 0.0f;
            #pragma unroll
            for (int i = 0; i < 8; ++i) {
                const float4 kv = kr[i];      // one K load, two dot products
                qk0 += kv.x*sQ[0][4*i+0] + kv.y*sQ[0][4*i+1]
                     + kv.z*sQ[0][4*i+2] + kv.w*sQ[0][4*i+3];
                qk1 += kv.x*sQ[1][4*i+0] + kv.y*sQ[1][4*i+1]
                     + kv.z*sQ[1][4*i+2] + kv.w*sQ[1][4*i+3];
            }
            if (live0) {
                const float x = pv0 + bp0;
                l0 = (qk0 - logf(1.0f + expf(-x))) * scale;
            }
            if (live1) {
                const float x = pv1 + bp0;
                l1 = (qk1 - logf(1.0f + expf(-x))) * scale;
            }
        }
        sLogit[0][tid] = l0;
        sLogit[1][tid] = l1;
    }
    __syncthreads();

    // ---- softmax over 200 logits, both rows (all-NEG -> uniform 1/200) ----
    const float v0 = (tid < LL) ? sLogit[0][tid] : -INFINITY;
    const float v1 = (tid < LL) ? sLogit[1][tid] : -INFINITY;
    float m0 = v0, m1 = v1;
    #pragma unroll
    for (int s = 1; s < 64; s <<= 1) {
        m0 = fmaxf(m0, __shfl_xor(m0, s, 64));
        m1 = fmaxf(m1, __shfl_xor(m1, s, 64));
    }
    if (lane == 0) { sRed[0][wave] = m0; sRed[1][wave] = m1; }
    __syncthreads();
    const float rmax0 = fmaxf(fmaxf(sRed[0][0], sRed[0][1]),
                              fmaxf(sRed[0][2], sRed[0][3]));
    const float rmax1 = fmaxf(fmaxf(sRed[1][0], sRed[1][1]),
                              fmaxf(sRed[1][2], sRed[1][3]));

    const float e0 = (tid < LL) ? expf(v0 - rmax0) : 0.0f;
    const float e1 = (tid < LL) ? expf(v1 - rmax1) : 0.0f;
    float s0 = e0, s1 = e1;
    #pragma unroll
    for (int s = 1; s < 64; s <<= 1) {
        s0 += __shfl_xor(s0, s, 64);
        s1 += __shfl_xor(s1, s, 64);
    }
    if (lane == 0) { sRed[0][4 + wave] = s0; sRed[1][4 + wave] = s1; }
    __syncthreads();
    const float rsum0 = sRed[0][4] + sRed[0][5] + sRed[0][6] + sRed[0][7];
    const float rsum1 = sRed[1][4] + sRed[1][5] + sRed[1][6] + sRed[1][7];
    const float a0 = e0 * (1.0f / rsum0);
    const float a1 = e1 * (1.0f / rsum1);

    if (tid < LL) {
        sLogit[0][tid] = a0;
        sLogit[1][tid] = a1;
        attn_out[((size_t)hb*LL + q0)*LL + tid] = a0;
        attn_out[((size_t)hb*LL + q1)*LL + tid] = a1;
    }
    __syncthreads();

    // ---- out[d] = sum_k a[k] * V[hb][k][d], both rows share the V load ----
    {
        const int d = tid & 31;
        const int g = tid >> 5;            // 0..7, 25 keys each
        float acc0 = 0.0f, acc1 = 0.0f;
        for (int k = g*25; k < g*25 + 25; ++k) {
            const float vv = Vs[(hb*LL + k)*HSS + d];
            acc0 = fmaf(sLogit[0][k], vv, acc0);
            acc1 = fmaf(sLogit[1][k], vv, acc1);
        }
        sO[0][g][d] = acc0;
        sO[1][g][d] = acc1;
        __syncthreads();
        if (tid < 2*HSS) {
            const int which = tid >> 5, d2 = tid & 31;
            float o = 0.0f;
            #pragma unroll
            for (int g2 = 0; g2 < 8; ++g2) o += sO[which][g2][d2];
            out[((size_t)b*LL + (which ? q1 : q0))*HH + head*HSS + d2] = o;
        }
    }
}

// ---------------------------------------------------------------------------
extern "C" void kernel_launch(void* const* d_in, const int* in_sizes, int n_in,
                              void* d_out, int out_size, void* d_ws, size_t ws_size,
                              hipStream_t stream) {
    const float* queries = (const float*)d_in[0];
    const float* keys    = (const float*)d_in[1];
    const float* values  = (const float*)d_in[2];
    const float* T       = (const float*)d_in[3];
    const int*   tmask   = (const int*)d_in[4];
    // d_in[5] = attn_mask (causal triu, computed on the fly -> unused)
    const float* Wq = (const float*)d_in[6];
    const float* bq = (const float*)d_in[7];
    const float* Wk = (const float*)d_in[8];
    const float* bk = (const float*)d_in[9];
    const float* Wv = (const float*)d_in[10];
    const float* bv = (const float*)d_in[11];
    const float* Wt = (const float*)d_in[12];
    const float* bt = (const float*)d_in[13];
    const float* Wp = (const float*)d_in[14];
    const float* bp = (const float*)d_in[15];

    float* Qs = (float*)d_ws;
    float* Ks = Qs + HB*LL*HSS;
    float* Vs = Ks + HB*LL*HSS;
    unsigned short* WtT = (unsigned short*)(Vs + HB*LL*HSS);

    float* out      = (float*)d_out;
    float* attn_out = out + BB*LL*HH;            // doubles as Plog scratch

    proj_kernel<<<BB*LL, 64, 0, stream>>>(queries, keys, values,
                                          Wq, bq, Wk, bk, Wv, bv,
                                          Wt, WtT, Qs, Ks, Vs);

    dim3 mgrid((TRI + ROWS - 1) / ROWS, HB);     // 32 x 64 = 2048 blocks
    mlp_kernel<<<mgrid, 256, 0, stream>>>(T, WtT, bt, Wp, attn_out);

    dim3 agrid(LL/2, HB);                        // 100 x 64, 2 q per block
    attn2_kernel<<<agrid, 256, 0, stream>>>(Qs, Ks, Vs, tmask, bp,
                                            out, attn_out);
}